// Round 1
// baseline (266.829 us; speedup 1.0000x reference)
//
#include <hip/hip_runtime.h>

// LRN (buggy-keras window) on x:(64,56,56,192) fp32 NHWC.
// window for channel c: [max(c-2,0), min(2c+3, C)); scale=(sum*2e-5+1)^0.75; out=x/scale
//
// R4: latency-bound fix (R3 had all pipes idle: VALU 14%, HBM 32%, LDS small, occ 71%).
//  - LDS table + __syncthreads REMOVED: the odd-prefix gather cs[24*sub+2k+3] lives
//    in-register as pre[{1,3,5,7,9,11}] of lanes 2sub/2sub+1/2sub+2 -> 12 ds_bpermute
//    with 3 precomputed lane addresses. No LDS write, no barrier, no LDS-RAW wait.
//  - 2 pixel-batches per wave: all 6 dwordx4 loads issued up front; batch1's HBM
//    latency hides under batch0's compute chain (2x MLP per wave, half the waves).
// 16 lanes/pixel, 12 channels/lane, 4 pixels/wave/batch, 2 batches, 4 waves/block.
// (1+e)^-0.75 via cubic series (e<=~0.01 -> err <1e-7 vs thr 0.108).

constexpr int   C     = 192;
constexpr int   LPP   = 16;             // lanes per pixel
constexpr int   CPL   = 12;             // channels per lane
constexpr int   PPW   = 4;              // pixels per wave per batch
constexpr int   NB    = 2;              // batches per wave
constexpr int   WPB   = 4;              // waves per block
constexpr int   PPB   = PPW * NB * WPB; // 32 pixels per block
constexpr int   BLOCK = 256;
constexpr float AON   = 0.0001f / 5.0f; // alpha/n = 2e-5

__device__ __forceinline__ float bperm(int byteaddr, float v) {
  return __int_as_float(__builtin_amdgcn_ds_bpermute(byteaddr, __float_as_int(v)));
}

__device__ __forceinline__ void lrn_pixel(const float xr[CPL], float4* __restrict__ ob,
                                          int sub, int adr0, int adr1, int adr2) {
  // ---- chunk total (2-way split chain) ----
  float ta = 0.0f, tb = 0.0f;
#pragma unroll
  for (int k = 0; k < CPL; k += 2) {
    ta = fmaf(xr[k], xr[k], ta);
    tb = fmaf(xr[k + 1], xr[k + 1], tb);
  }
  const float T = ta + tb;

  // ---- inclusive scan of 16 chunk totals within the pixel's lane group ----
  float incl = T;
#pragma unroll
  for (int off = 1; off < LPP; off <<= 1) {
    const float t = __shfl_up(incl, off, LPP);
    if (sub >= off) incl += t;
  }
  const float base  = incl - T;                    // cs[12*sub]
  const float total = __shfl(incl, LPP - 1, LPP);  // cs[192]

  // ---- exclusive prefix over own 12 channels: pre[k] = cs[12*sub+k] ----
  float pre[CPL];
  float run = base;
#pragma unroll
  for (int k = 0; k < CPL; ++k) {
    pre[k] = run;
    run = fmaf(xr[k], xr[k], run);
  }

  // ---- head boundary values for k=0,1 from neighbor lane ----
  float hb0 = __shfl_up(pre[CPL - 2], 1, LPP);     // cs[12*sub - 2]
  float hb1 = __shfl_up(pre[CPL - 1], 1, LPP);     // cs[12*sub - 1]
  if (sub == 0) { hb0 = 0.0f; hb1 = 0.0f; }

  // ---- gather cs[end], end = 24*sub + 2k + 3 (odd) -> register bpermute ----
  // owner lane = end/12 in {2sub, 2sub+1, 2sub+2}, slot = end%12 (odd).
  // Out-of-group sources (sub>=7 edge) wrap via &15; those channels use `total`.
  float g[CPL];
  g[0]  = bperm(adr0, pre[3]);
  g[1]  = bperm(adr0, pre[5]);
  g[2]  = bperm(adr0, pre[7]);
  g[3]  = bperm(adr0, pre[9]);
  g[4]  = bperm(adr0, pre[11]);
  g[5]  = bperm(adr1, pre[1]);
  g[6]  = bperm(adr1, pre[3]);
  g[7]  = bperm(adr1, pre[5]);
  g[8]  = bperm(adr1, pre[7]);
  g[9]  = bperm(adr1, pre[9]);
  g[10] = bperm(adr1, pre[11]);
  g[11] = bperm(adr2, pre[1]);

  // ---- windowed sums + series scale + store ----
#pragma unroll
  for (int g3 = 0; g3 < 3; ++g3) {
    float q[4];
#pragma unroll
    for (int kk = 0; kk < 4; ++kk) {
      const int k = g3 * 4 + kk;
      const int c = CPL * sub + k;                 // channel within pixel
      const float csh = (k >= 2) ? pre[k - 2] : (k == 0 ? hb0 : hb1);
      const float cse = (c < 95) ? g[k] : total;   // end<192 iff c<95
      const float eps = (cse - csh) * AON;         // in [0, ~0.01]
      // (1+e)^-0.75 ~= 1 - 0.75e + 0.65625e^2 - 0.6015625e^3
      const float inv = fmaf(eps, fmaf(eps, fmaf(eps, -0.6015625f, 0.65625f), -0.75f), 1.0f);
      q[kk] = xr[k] * inv;
    }
    ob[sub * 3 + g3] = make_float4(q[0], q[1], q[2], q[3]);
  }
}

__global__ __launch_bounds__(BLOCK, 6) void lrn_kernel(
    const float* __restrict__ x, float* __restrict__ out, int npix) {
  const int tid  = threadIdx.x;
  const int lane = tid & 63;
  const int w    = tid >> 6;
  const int sub  = lane & 15;   // lane within pixel
  const int pl   = lane >> 4;   // pixel within wave (per batch)

  long long p0 = (long long)blockIdx.x * PPB + w * (PPW * NB) + pl;
  long long p1 = p0 + PPW;
  if (p0 > npix - 1) p0 = npix - 1;   // benign duplicate work on tails
  if (p1 > npix - 1) p1 = npix - 1;

  const float4* __restrict__ xb0 = (const float4*)(x + (size_t)p0 * C);
  const float4* __restrict__ xb1 = (const float4*)(x + (size_t)p1 * C);
  float4* __restrict__ ob0 = (float4*)(out + (size_t)p0 * C);
  float4* __restrict__ ob1 = (float4*)(out + (size_t)p1 * C);

  // ---- issue all 6 loads up front (2x MLP; batch1 latency hides under batch0) ----
  const float4 u0 = xb0[sub * 3 + 0];
  const float4 u1 = xb0[sub * 3 + 1];
  const float4 u2 = xb0[sub * 3 + 2];
  const float4 v0 = xb1[sub * 3 + 0];
  const float4 v1 = xb1[sub * 3 + 1];
  const float4 v2 = xb1[sub * 3 + 2];

  // bpermute byte addresses for source lanes 2sub, 2sub+1, 2sub+2 (within 16-group)
  const int gb   = lane & 48;         // group base lane
  const int s2   = sub * 2;
  const int adr0 = (gb | (s2 & 15)) << 2;
  const int adr1 = (gb | ((s2 + 1) & 15)) << 2;
  const int adr2 = (gb | ((s2 + 2) & 15)) << 2;

  float xr0[CPL] = {u0.x, u0.y, u0.z, u0.w, u1.x, u1.y, u1.z, u1.w,
                    u2.x, u2.y, u2.z, u2.w};
  lrn_pixel(xr0, ob0, sub, adr0, adr1, adr2);

  float xr1[CPL] = {v0.x, v0.y, v0.z, v0.w, v1.x, v1.y, v1.z, v1.w,
                    v2.x, v2.y, v2.z, v2.w};
  lrn_pixel(xr1, ob1, sub, adr0, adr1, adr2);
}

extern "C" void kernel_launch(void* const* d_in, const int* in_sizes, int n_in,
                              void* d_out, int out_size, void* d_ws, size_t ws_size,
                              hipStream_t stream) {
  const float* x   = (const float*)d_in[0];
  float*       out = (float*)d_out;
  const int npix = in_sizes[0] / C;             // 64*56*56 = 200704 (= 32 * 6272)
  const int grid = (npix + PPB - 1) / PPB;      // 6272
  lrn_kernel<<<grid, BLOCK, 0, stream>>>(x, out, npix);
}

// Round 2
// 259.950 us; speedup vs baseline: 1.0265x; 1.0265x over previous
//
#include <hip/hip_runtime.h>

// LRN (buggy-keras window) on x:(64,56,56,192) fp32 NHWC.
// window for channel c: [max(c-2,0), min(2c+3, C)); scale=(sum*2e-5+1)^0.75; out=x/scale
//
// R5: coalescing fix. R3 (LDS) and R4 (bpermute) were IDENTICAL at 93us / 2.55 TB/s with
// all pipes idle -> the shared stride-48B per-instruction access pattern is the wall
// (each VMEM inst touched 48 lines, 3x the ideal; fill kernel hits 6.6 TB/s contiguous).
// Fix: interleaved ownership. Lane sub owns float4s {sub, 16+sub, 32+sub} of its pixel
// -> every load/store instruction is 256B-contiguous per 16-lane group (16 full lines
// per wave inst = ideal). Channels per lane: slot s owns c = 64s + 4sub + k.
//  - prefix scan: 3 independent 16-wide scans (chunks 16s+sub), stitched by slot totals.
//  - cs[end] gather (end=2c+3 odd): 12 ds_bpermute; s=0 needs slot0/slot1 select
//    (8 bperm + 4 cndmask), s=1 is uniform slot2 (4 bperm), s=2 always uses total.
//  - heads cs[c-2]: own regs (k>=2) or shfl_up(1) with cross-slot lane-15 broadcast fix.
// (1+e)^-0.75 via cubic series (e<=~0.01 -> err <1e-7 vs thr 0.108).

constexpr int   C     = 192;
constexpr int   LPP   = 16;             // lanes per pixel
constexpr int   PPW   = 4;              // pixels per wave
constexpr int   WPB   = 4;              // waves per block
constexpr int   PPB   = PPW * WPB;      // 16 pixels per block
constexpr int   BLOCK = 256;
constexpr float AON   = 0.0001f / 5.0f; // alpha/n = 2e-5

__device__ __forceinline__ float bperm(int byteaddr, float v) {
  return __int_as_float(__builtin_amdgcn_ds_bpermute(byteaddr, __float_as_int(v)));
}

__global__ __launch_bounds__(BLOCK, 6) void lrn_kernel(
    const float* __restrict__ x, float* __restrict__ out, int npix) {
  const int tid  = threadIdx.x;
  const int lane = tid & 63;
  const int w    = tid >> 6;
  const int sub  = lane & 15;   // lane within pixel
  const int pl   = lane >> 4;   // pixel within wave

  long long pix = (long long)blockIdx.x * PPB + w * PPW + pl;
  if (pix > npix - 1) pix = npix - 1;   // benign duplicate work on tails

  const float4* __restrict__ xb = (const float4*)(x + (size_t)pix * C);
  float4* __restrict__ ob       = (float4*)(out + (size_t)pix * C);

  // ---- coalesced loads: inst j covers bytes [256j, 256j+256) of the pixel row ----
  const float4 u0 = xb[sub];        // channels 4sub+0..3          (slot 0)
  const float4 u1 = xb[16 + sub];   // channels 64+4sub+0..3       (slot 1)
  const float4 u2 = xb[32 + sub];   // channels 128+4sub+0..3      (slot 2)

  float xs[3][4] = {{u0.x, u0.y, u0.z, u0.w},
                    {u1.x, u1.y, u1.z, u1.w},
                    {u2.x, u2.y, u2.z, u2.w}};

  // ---- chunk sums q[s] = sum of squares of slot s (chunk index m = 16s + sub) ----
  float q[3];
#pragma unroll
  for (int s = 0; s < 3; ++s)
    q[s] = fmaf(xs[s][0], xs[s][0],
           fmaf(xs[s][1], xs[s][1],
           fmaf(xs[s][2], xs[s][2], xs[s][3] * xs[s][3])));

  // ---- three independent 16-wide inclusive scans (ILP: 3 chains) ----
  float i0 = q[0], i1 = q[1], i2 = q[2];
#pragma unroll
  for (int off = 1; off < LPP; off <<= 1) {
    const float t0 = __shfl_up(i0, off, LPP);
    const float t1 = __shfl_up(i1, off, LPP);
    const float t2 = __shfl_up(i2, off, LPP);
    if (sub >= off) { i0 += t0; i1 += t1; i2 += t2; }
  }
  const float T0 = __shfl(i0, LPP - 1, LPP);
  const float T1 = __shfl(i1, LPP - 1, LPP);
  const float T2 = __shfl(i2, LPP - 1, LPP);
  const float total = T0 + T1 + T2;                    // cs[192]
  const float E[3] = { i0 - q[0], T0 + i1 - q[1], T0 + T1 + i2 - q[2] };

  // ---- per-slot channel prefixes: p[s][k] = cs[64s + 4sub + k] ----
  float p[3][4];
#pragma unroll
  for (int s = 0; s < 3; ++s) {
    float run = E[s];
#pragma unroll
    for (int k = 0; k < 4; ++k) { p[s][k] = run; run = fmaf(xs[s][k], xs[s][k], run); }
  }

  // ---- head boundaries: hb0[s]=cs[64s+4sub-2], hb1[s]=cs[64s+4sub-1] ----
  float hb0[3], hb1[3];
#pragma unroll
  for (int s = 0; s < 3; ++s) {
    hb0[s] = __shfl_up(p[s][2], 1, LPP);
    hb1[s] = __shfl_up(p[s][3], 1, LPP);
  }
  const float B02 = __shfl(p[0][2], LPP - 1, LPP);   // cs[62]
  const float B03 = __shfl(p[0][3], LPP - 1, LPP);   // cs[63]
  const float B12 = __shfl(p[1][2], LPP - 1, LPP);   // cs[126]
  const float B13 = __shfl(p[1][3], LPP - 1, LPP);   // cs[127]
  if (sub == 0) {
    hb0[0] = 0.0f; hb1[0] = 0.0f;    // c=0,1 -> head=0 -> cs[0]=0
    hb0[1] = B02;  hb1[1] = B03;
    hb0[2] = B12;  hb1[2] = B13;
  }

  // ---- gather cs[end], end = 2c+3 = 128s + 8sub + 2k + 3 (valid iff c <= 94) ----
  // owner chunk m = end/4, owner lane = m & 15, register = p[m/16][end & 3].
  // s=0: m = 2sub + {0,1,1,2}, reg slot = m/16 in {0,1} -> 2 bperm + select.
  // s=1: m = 32 + 2sub + {0,1,1,2}, reg slot = 2 uniformly -> 1 bperm.
  const int gb = lane & 48;                 // group base lane
  const int a0 = (gb | ((2 * sub)     & 15)) << 2;
  const int a1 = (gb | ((2 * sub + 1) & 15)) << 2;
  const int a2 = (gb | ((2 * sub + 2) & 15)) << 2;

  float ge0[4], ge1[4];
  {
    const float r00 = bperm(a0, p[0][3]), r01 = bperm(a0, p[1][3]);  // k=0 (pos 3)
    const float r10 = bperm(a1, p[0][1]), r11 = bperm(a1, p[1][1]);  // k=1 (pos 1)
    const float r20 = bperm(a1, p[0][3]), r21 = bperm(a1, p[1][3]);  // k=2 (pos 3)
    const float r30 = bperm(a2, p[0][1]), r31 = bperm(a2, p[1][1]);  // k=3 (pos 1)
    ge0[0] = (sub < 8) ? r00 : r01;       // m=2sub   < 16 ?
    ge0[1] = (sub < 8) ? r10 : r11;       // m=2sub+1 < 16 ?
    ge0[2] = (sub < 8) ? r20 : r21;
    ge0[3] = (sub < 7) ? r30 : r31;       // m=2sub+2 < 16 ?
    ge1[0] = bperm(a0, p[2][3]);
    ge1[1] = bperm(a1, p[2][1]);
    ge1[2] = bperm(a1, p[2][3]);
    ge1[3] = bperm(a2, p[2][1]);
  }

  // ---- windowed sums + series scale + coalesced stores ----
#pragma unroll
  for (int s = 0; s < 3; ++s) {
    float r[4];
#pragma unroll
    for (int k = 0; k < 4; ++k) {
      const float csh = (k >= 2) ? p[s][k - 2] : (k == 0 ? hb0[s] : hb1[s]);
      float cse;
      if (s == 0)      cse = ge0[k];                                // c = 4sub+k <= 63
      else if (s == 1) cse = (4 * sub + k >= 31) ? total : ge1[k];  // c=95 edge -> total
      else             cse = total;                                 // c >= 128
      const float eps = (cse - csh) * AON;        // in [0, ~0.01]
      // (1+e)^-0.75 ~= 1 - 0.75e + 0.65625e^2 - 0.6015625e^3
      const float inv = fmaf(eps, fmaf(eps, fmaf(eps, -0.6015625f, 0.65625f), -0.75f), 1.0f);
      r[k] = xs[s][k] * inv;
    }
    ob[16 * s + sub] = make_float4(r[0], r[1], r[2], r[3]);
  }
}

extern "C" void kernel_launch(void* const* d_in, const int* in_sizes, int n_in,
                              void* d_out, int out_size, void* d_ws, size_t ws_size,
                              hipStream_t stream) {
  const float* x   = (const float*)d_in[0];
  float*       out = (float*)d_out;
  const int npix = in_sizes[0] / C;             // 64*56*56 = 200704 (= 16 * 12544)
  const int grid = (npix + PPB - 1) / PPB;      // 12544
  lrn_kernel<<<grid, BLOCK, 0, stream>>>(x, out, npix);
}